// Round 1
// baseline (3670.871 us; speedup 1.0000x reference)
//
#include <hip/hip_runtime.h>
#include <hip/hip_bf16.h>
#include <stdint.h>

#define H_  10
#define B_  16384
#define F_  4
#define D_  2048
#define C_  2

typedef __attribute__((ext_vector_type(8))) short  short8;
typedef __attribute__((ext_vector_type(4))) float  floatx4;

typedef const uint32_t __attribute__((address_space(1))) gu32;
typedef uint32_t       __attribute__((address_space(3))) lu32;

__device__ __forceinline__ void async16(const void* g, void* l) {
    __builtin_amdgcn_global_load_lds((gu32*)g, (lu32*)l, 16, 0, 0);
}

__device__ __forceinline__ uint32_t f2bf(float f) {
    union { float f; uint32_t u; } a; a.f = f;
    uint32_t u = a.u;
    u += 0x7FFF + ((u >> 16) & 1);     // RNE (finite values only here)
    return u >> 16;
}
__device__ __forceinline__ uint32_t pack2bf(float a, float b) {
    return f2bf(a) | (f2bf(b) << 16);
}

// ---------------------------------------------------------------------------
// ws layout (bytes):
//   0          : W21t bf16 [H][D][D]  (n-major, k-contig)   83,886,080
//   83886080   : W22t bf16 [H][D][D]                        83,886,080
//   167772160  : acc31 f32 [H][B_][C_]                       1,310,720
//   169082880  : acc32 f32 [H][B_][C_]                       1,310,720
// ---------------------------------------------------------------------------

// Transpose + fp32->bf16 convert: W2x[h][k][n] -> W2xt[h][n][k]
__global__ __launch_bounds__(256) void k_convert(
    const float* __restrict__ W21, const float* __restrict__ W22,
    uint16_t* __restrict__ W21t, uint16_t* __restrict__ W22t)
{
    __shared__ float tile[64][65];
    const int z = blockIdx.z;
    const int h = z % H_;
    const float* src = (z < H_ ? W21 : W22) + (size_t)h * D_ * D_;
    uint16_t*   dst  = (z < H_ ? W21t : W22t) + (size_t)h * D_ * D_;
    const int k0 = blockIdx.x * 64, n0 = blockIdx.y * 64;
    const int t = threadIdx.x;

    const int c4 = (t & 15) * 4;
    const int rb = (t >> 4) * 4;
#pragma unroll
    for (int i = 0; i < 4; i++) {
        const float4 v = *(const float4*)(src + (size_t)(k0 + rb + i) * D_ + n0 + c4);
        tile[rb + i][c4 + 0] = v.x; tile[rb + i][c4 + 1] = v.y;
        tile[rb + i][c4 + 2] = v.z; tile[rb + i][c4 + 3] = v.w;
    }
    __syncthreads();
    const int n = t >> 2;
    const int cb = (t & 3) * 2;
#pragma unroll
    for (int j = 0; j < 2; j++) {
        const int kk = (cb + j) * 8;
        uint32_t pk[4];
#pragma unroll
        for (int e = 0; e < 4; e++)
            pk[e] = pack2bf(tile[kk + 2 * e][n], tile[kk + 2 * e + 1][n]);
        *(uint4*)(dst + (size_t)(n0 + n) * D_ + k0 + kk) = make_uint4(pk[0], pk[1], pk[2], pk[3]);
    }
}

__global__ __launch_bounds__(256) void k_zero(uint4* p, int n4) {
    const int i = blockIdx.x * 256 + threadIdx.x;
    if (i < n4) p[i] = make_uint4(0u, 0u, 0u, 0u);
}

// ---------------------------------------------------------------------------
// Fused: h1 = relu(x@W1+b1) (VALU, in-block) ; x2p = relu(h1@W2p + b2p) (MFMA)
//        acc3p[h][m][c] += sum_n x2p[m][n] * W3p[n][c]   (epilogue, atomics)
// Tile: 128(m) x 128(n) x K=2048, BK=64, both paths p=0,1 per block.
// ---------------------------------------------------------------------------
__global__ __launch_bounds__(256, 2) void k_gemm(
    const float* __restrict__ x, const float* __restrict__ W1, const float* __restrict__ b1,
    const uint16_t* __restrict__ W21t, const uint16_t* __restrict__ W22t,
    const float* __restrict__ b21, const float* __restrict__ b22,
    const float* __restrict__ W31, const float* __restrict__ W32,
    float* __restrict__ acc31, float* __restrict__ acc32)
{
    // A tile 128x64 bf16, swizzled: (m, chunk) at uint4 index m*8 + (chunk ^ (m&7))
    __shared__ uint4 At[1024];
    __shared__ uint4 Bt0[1024];   // B tiles 128(n)x64(k), same swizzle on (n, chunk)
    __shared__ uint4 Bt1[1024];

    const int h = blockIdx.z;
    const int mBase = blockIdx.x * 128;
    const int nBase = blockIdx.y * 128;
    const int t = threadIdx.x;
    const int lane = t & 63, wid = t >> 6;
    const int q = lane >> 4, c15 = lane & 15;
    const int wm = wid >> 1, wn = wid & 1;

    // ---- A-compute mapping: thread owns m = mg..mg+3, k = k0..k0+7 of each chunk
    const int k0 = (t & 7) * 8;
    const int mg = (t >> 3) * 4;

    float xv[4][4];
#pragma unroll
    for (int i = 0; i < 4; i++) {
        const float4 v = *(const float4*)(x + (size_t)(mBase + mg + i) * F_);
        xv[i][0] = v.x; xv[i][1] = v.y; xv[i][2] = v.z; xv[i][3] = v.w;
    }

    // ---- B staging source mapping (per-lane, swizzle folded into source index)
    const int nb = wid * 32 + (lane >> 3);                 // n row for i=0
    const int chunk = (lane & 7) ^ ((lane >> 3) & 7);      // k-chunk this lane fetches
    const uint16_t* bsrc0 = W21t + (size_t)h * D_ * D_ + (size_t)(nBase + nb) * D_ + chunk * 8;
    const uint16_t* bsrc1 = W22t + (size_t)h * D_ * D_ + (size_t)(nBase + nb) * D_ + chunk * 8;

    const float* W1h = W1 + (size_t)h * F_ * D_;
    const float* b1h = b1 + (size_t)h * D_;

    floatx4 acc0[4][4], acc1[4][4];
    const floatx4 z4 = {0.f, 0.f, 0.f, 0.f};
#pragma unroll
    for (int mi = 0; mi < 4; mi++)
#pragma unroll
        for (int ni = 0; ni < 4; ni++) { acc0[mi][ni] = z4; acc1[mi][ni] = z4; }

    for (int kt = 0; kt < D_; kt += 64) {
        // W1/b1 chunk loads first (so their waitcnt doesn't drain the DMA queue)
        float w1v[4][8], b1v[8];
        {
            const float4 bb0 = *(const float4*)(b1h + kt + k0);
            const float4 bb1 = *(const float4*)(b1h + kt + k0 + 4);
            b1v[0] = bb0.x; b1v[1] = bb0.y; b1v[2] = bb0.z; b1v[3] = bb0.w;
            b1v[4] = bb1.x; b1v[5] = bb1.y; b1v[6] = bb1.z; b1v[7] = bb1.w;
#pragma unroll
            for (int f = 0; f < 4; f++) {
                const float4 a0 = *(const float4*)(W1h + f * D_ + kt + k0);
                const float4 a1 = *(const float4*)(W1h + f * D_ + kt + k0 + 4);
                w1v[f][0] = a0.x; w1v[f][1] = a0.y; w1v[f][2] = a0.z; w1v[f][3] = a0.w;
                w1v[f][4] = a1.x; w1v[f][5] = a1.y; w1v[f][6] = a1.z; w1v[f][7] = a1.w;
            }
        }
        // async B staging (8 x 1KB wave-instructions for the block)
#pragma unroll
        for (int i = 0; i < 4; i++) {
            async16(bsrc0 + kt + i * (8 * D_), (char*)Bt0 + wid * 4096 + i * 1024);
            async16(bsrc1 + kt + i * (8 * D_), (char*)Bt1 + wid * 4096 + i * 1024);
        }
        // h1 compute -> A tile (bf16, swizzled)
#pragma unroll
        for (int i = 0; i < 4; i++) {
            const int m = mg + i;
            float hv[8];
#pragma unroll
            for (int j = 0; j < 8; j++) hv[j] = b1v[j];
#pragma unroll
            for (int f = 0; f < 4; f++)
#pragma unroll
                for (int j = 0; j < 8; j++) hv[j] = fmaf(xv[i][f], w1v[f][j], hv[j]);
            uint32_t pk[4];
#pragma unroll
            for (int e = 0; e < 4; e++)
                pk[e] = pack2bf(fmaxf(hv[2 * e], 0.f), fmaxf(hv[2 * e + 1], 0.f));
            At[m * 8 + ((t & 7) ^ (m & 7))] = make_uint4(pk[0], pk[1], pk[2], pk[3]);
        }
        __syncthreads();
        // MFMA phase
#pragma unroll
        for (int s = 0; s < 2; s++) {
            short8 af[4];
#pragma unroll
            for (int mi = 0; mi < 4; mi++) {
                const int m = wm * 64 + mi * 16 + c15;
                af[mi] = __builtin_bit_cast(short8, At[m * 8 + ((s * 4 + q) ^ (c15 & 7))]);
            }
#pragma unroll
            for (int ni = 0; ni < 4; ni++) {
                const int n = wn * 64 + ni * 16 + c15;
                const int bidx = n * 8 + ((s * 4 + q) ^ (c15 & 7));
                const short8 bf0 = __builtin_bit_cast(short8, Bt0[bidx]);
#pragma unroll
                for (int mi = 0; mi < 4; mi++)
                    acc0[mi][ni] = __builtin_amdgcn_mfma_f32_16x16x32_bf16(af[mi], bf0, acc0[mi][ni], 0, 0, 0);
                const short8 bf1 = __builtin_bit_cast(short8, Bt1[bidx]);
#pragma unroll
                for (int mi = 0; mi < 4; mi++)
                    acc1[mi][ni] = __builtin_amdgcn_mfma_f32_16x16x32_bf16(af[mi], bf1, acc1[mi][ni], 0, 0, 0);
            }
        }
        __syncthreads();
    }

    // ---- Epilogue: bias + relu + (.)@W3 reduction, shuffle-reduce, atomics
#pragma unroll
    for (int p = 0; p < 2; p++) {
        const float* b2p = (p == 0 ? b21 : b22) + (size_t)h * D_;
        const float* W3p = (p == 0 ? W31 : W32) + (size_t)h * D_ * C_;
        float* ab = (p == 0 ? acc31 : acc32) + (size_t)h * B_ * C_;
        float w3x[4], w3y[4], bs[4];
#pragma unroll
        for (int ni = 0; ni < 4; ni++) {
            const int n = nBase + wn * 64 + ni * 16 + c15;
            bs[ni] = b2p[n];
            const float2 w2 = *(const float2*)(W3p + n * 2);
            w3x[ni] = w2.x; w3y[ni] = w2.y;
        }
        float s0[16], s1[16];
#pragma unroll
        for (int mi = 0; mi < 4; mi++)
#pragma unroll
            for (int r = 0; r < 4; r++) {
                float t0 = 0.f, t1 = 0.f;
#pragma unroll
                for (int ni = 0; ni < 4; ni++) {
                    float v = (p == 0 ? acc0[mi][ni][r] : acc1[mi][ni][r]) + bs[ni];
                    v = fmaxf(v, 0.f);
                    t0 = fmaf(v, w3x[ni], t0);
                    t1 = fmaf(v, w3y[ni], t1);
                }
                s0[mi * 4 + r] = t0; s1[mi * 4 + r] = t1;
            }
#pragma unroll
        for (int off = 1; off < 16; off <<= 1)
#pragma unroll
            for (int i = 0; i < 16; i++) {
                s0[i] += __shfl_xor(s0[i], off, 64);
                s1[i] += __shfl_xor(s1[i], off, 64);
            }
        if (c15 == 0) {
#pragma unroll
            for (int mi = 0; mi < 4; mi++)
#pragma unroll
                for (int r = 0; r < 4; r++) {
                    const int row = mBase + wm * 64 + mi * 16 + q * 4 + r;
                    atomicAdd(&ab[row * C_ + 0], s0[mi * 4 + r]);
                    atomicAdd(&ab[row * C_ + 1], s1[mi * 4 + r]);
                }
        }
    }
}

// ---------------------------------------------------------------------------
// Finalize: biases, sigmoid head, CBF-QP correction, softmax-weighted mix
// ---------------------------------------------------------------------------
__global__ __launch_bounds__(256) void k_final(
    const float* __restrict__ x,
    const float* __restrict__ acc31, const float* __restrict__ acc32,
    const float* __restrict__ b31, const float* __restrict__ b32,
    const float* __restrict__ wt, const float* __restrict__ mean,
    const float* __restrict__ stdv, float* __restrict__ out)
{
    const int b = blockIdx.x * 256 + threadIdx.x;
    const float4 xb = *(const float4*)(x + (size_t)b * 4);
    const float px = xb.x * stdv[0] + mean[0];
    const float py = xb.y * stdv[1] + mean[1];
    const float th = xb.z * stdv[2] + mean[2];
    const float v  = xb.w * stdv[3] + mean[3];
    const float dx = px - 40.0f, dy = py - 15.0f;
    const float st = sinf(th), ct = cosf(th);
    const float barrier = dx * dx + dy * dy - 36.0f;
    const float bdot = 2.f * dx * v * ct + 2.f * dy * v * st;
    const float Lf2b = 2.f * v * v;
    const float G0 = -(-2.f * dx * v * st + 2.f * dy * v * ct);
    const float G1 = -(2.f * dx * ct + 2.f * dy * st);
    const float GG = G0 * G0 + G1 * G1;

    float we[H_];
    float wmax = wt[0];
    for (int h = 1; h < H_; h++) wmax = fmaxf(wmax, wt[h]);
    float wsum = 0.f;
    for (int h = 0; h < H_; h++) { we[h] = expf(wt[h] - wmax); wsum += we[h]; }

    float o0 = 0.f, o1 = 0.f;
#pragma unroll
    for (int h = 0; h < H_; h++) {
        const size_t idx = ((size_t)h * B_ + b) * 2;
        const float x310 = acc31[idx]     + b31[h * 2];
        const float x311 = acc31[idx + 1] + b31[h * 2 + 1];
        const float z0 = acc32[idx]     + b32[h * 2];
        const float z1 = acc32[idx + 1] + b32[h * 2 + 1];
        const float x320 = 4.f / (1.f + expf(-z0));
        const float x321 = 4.f / (1.f + expf(-z1));
        const float hr = Lf2b + (x320 + x321) * bdot + x320 * x321 * barrier;
        const float Gu = G0 * x310 + G1 * x311;
        const float lam = fmaxf(Gu - hr, 0.f) / GG;
        o0 += we[h] * (x310 - lam * G0);
        o1 += we[h] * (x311 - lam * G1);
    }
    out[b * 2]     = o0 / wsum;
    out[b * 2 + 1] = o1 / wsum;
}

extern "C" void kernel_launch(void* const* d_in, const int* in_sizes, int n_in,
                              void* d_out, int out_size, void* d_ws, size_t ws_size,
                              hipStream_t stream)
{
    const float* x    = (const float*)d_in[0];
    const float* W1   = (const float*)d_in[1];
    const float* b1   = (const float*)d_in[2];
    const float* W21  = (const float*)d_in[3];
    const float* b21  = (const float*)d_in[4];
    const float* W22  = (const float*)d_in[5];
    const float* b22  = (const float*)d_in[6];
    const float* W31  = (const float*)d_in[7];
    const float* b31  = (const float*)d_in[8];
    const float* W32  = (const float*)d_in[9];
    const float* b32  = (const float*)d_in[10];
    const float* wt   = (const float*)d_in[11];
    const float* mean = (const float*)d_in[12];
    const float* stdv = (const float*)d_in[13];
    float* out = (float*)d_out;

    char* ws = (char*)d_ws;
    uint16_t* W21t = (uint16_t*)(ws);
    uint16_t* W22t = (uint16_t*)(ws + 83886080);
    float* acc31   = (float*)(ws + 167772160);
    float* acc32   = (float*)(ws + 169082880);

    k_convert<<<dim3(32, 32, 20), 256, 0, stream>>>(W21, W22, W21t, W22t);
    k_zero<<<dim3(640), 256, 0, stream>>>((uint4*)acc31, 163840);
    k_gemm<<<dim3(128, 16, 10), 256, 0, stream>>>(x, W1, b1, W21t, W22t,
                                                  b21, b22, W31, W32, acc31, acc32);
    k_final<<<dim3(64), 256, 0, stream>>>(x, acc31, acc32, b31, b32, wt, mean, stdv, out);
}

// Round 3
// 3566.939 us; speedup vs baseline: 1.0291x; 1.0291x over previous
//
#include <hip/hip_runtime.h>
#include <hip/hip_bf16.h>
#include <stdint.h>

#define H_  10
#define B_  16384
#define F_  4
#define D_  2048
#define C_  2

typedef __attribute__((ext_vector_type(8))) short  short8;
typedef __attribute__((ext_vector_type(4))) float  floatx4;
typedef __attribute__((ext_vector_type(2))) float  float2v;

typedef const uint32_t __attribute__((address_space(1))) gu32;
typedef uint32_t       __attribute__((address_space(3))) lu32;

__device__ __forceinline__ void async16(const void* g, void* l) {
    __builtin_amdgcn_global_load_lds((gu32*)g, (lu32*)l, 16, 0, 0);
}

// relu + round-half-up bf16 pack, branch-free, no intrinsic gambles:
// 2x v_max, 2x v_add, v_lshr, v_and, v_or
__device__ __forceinline__ uint32_t packbf(float a, float b) {
    a = fmaxf(a, 0.f); b = fmaxf(b, 0.f);
    const uint32_t ax = __builtin_bit_cast(uint32_t, a) + 0x8000u;
    const uint32_t bx = __builtin_bit_cast(uint32_t, b) + 0x8000u;
    return (ax >> 16) | (bx & 0xFFFF0000u);
}

// full-precision RNE pack (convert kernel only; off the hot path)
__device__ __forceinline__ uint32_t f2bf(float f) {
    union { float f; uint32_t u; } a; a.f = f;
    uint32_t u = a.u;
    u += 0x7FFF + ((u >> 16) & 1);
    return u >> 16;
}
__device__ __forceinline__ uint32_t pack2bf(float a, float b) {
    return f2bf(a) | (f2bf(b) << 16);
}

// ---------------------------------------------------------------------------
// ws layout (bytes) — total 170,393,600 (same as R0, proven in-budget):
//   0          : W21t bf16 [H][D][D]  (n-major, k-contig)   83,886,080
//   83886080   : W22t bf16 [H][D][D]                        83,886,080
//   167772160  : acc31 f32 [H][B_][C_]                       1,310,720
//   169082880  : acc32 f32 [H][B_][C_]                       1,310,720
// ---------------------------------------------------------------------------

__global__ __launch_bounds__(256) void k_convert(
    const float* __restrict__ W21, const float* __restrict__ W22,
    uint16_t* __restrict__ W21t, uint16_t* __restrict__ W22t)
{
    __shared__ float tile[64][65];
    const int z = blockIdx.z;
    const int h = z % H_;
    const float* src = (z < H_ ? W21 : W22) + (size_t)h * D_ * D_;
    uint16_t*   dst  = (z < H_ ? W21t : W22t) + (size_t)h * D_ * D_;
    const int k0 = blockIdx.x * 64, n0 = blockIdx.y * 64;
    const int t = threadIdx.x;

    const int c4 = (t & 15) * 4;
    const int rb = (t >> 4) * 4;
#pragma unroll
    for (int i = 0; i < 4; i++) {
        const float4 v = *(const float4*)(src + (size_t)(k0 + rb + i) * D_ + n0 + c4);
        tile[rb + i][c4 + 0] = v.x; tile[rb + i][c4 + 1] = v.y;
        tile[rb + i][c4 + 2] = v.z; tile[rb + i][c4 + 3] = v.w;
    }
    __syncthreads();
    const int n = t >> 2;
    const int cb = (t & 3) * 2;
#pragma unroll
    for (int j = 0; j < 2; j++) {
        const int kk = (cb + j) * 8;
        uint32_t pk[4];
#pragma unroll
        for (int e = 0; e < 4; e++)
            pk[e] = pack2bf(tile[kk + 2 * e][n], tile[kk + 2 * e + 1][n]);
        *(uint4*)(dst + (size_t)(n0 + n) * D_ + k0 + kk) = make_uint4(pk[0], pk[1], pk[2], pk[3]);
    }
}

__global__ __launch_bounds__(256) void k_zero(uint4* p, int n4) {
    const int i = blockIdx.x * 256 + threadIdx.x;
    if (i < n4) p[i] = make_uint4(0u, 0u, 0u, 0u);
}

// ---------------------------------------------------------------------------
// Fused: h1 = relu(x@W1+b1) (pk_fma VALU) ; x2p = relu(h1@W2p+b2p) (MFMA)
//        acc3p[h][m][c] += sum_n x2p[m][n] * W3p[n][c]   (epilogue, atomics)
// ---------------------------------------------------------------------------
__global__ __launch_bounds__(256, 2) void k_gemm(
    const float* __restrict__ x, const float* __restrict__ W1, const float* __restrict__ b1,
    const uint16_t* __restrict__ W21t, const uint16_t* __restrict__ W22t,
    const float* __restrict__ b21, const float* __restrict__ b22,
    const float* __restrict__ W31, const float* __restrict__ W32,
    float* __restrict__ acc31, float* __restrict__ acc32)
{
    __shared__ uint4 At[1024];    // A tile 128x64 bf16, idx m*8 + (chunk ^ (m&7))
    __shared__ uint4 Bt0[1024];   // B tiles 128(n)x64(k), same swizzle
    __shared__ uint4 Bt1[1024];

    const int h = blockIdx.z;
    const int mBase = blockIdx.x * 128;
    const int nBase = blockIdx.y * 128;
    const int t = threadIdx.x;
    const int lane = t & 63, wid = t >> 6;
    const int q = lane >> 4, c15 = lane & 15;
    const int wm = wid >> 1, wn = wid & 1;

    const int k0 = (t & 7) * 8;
    const int mg = (t >> 3) * 4;

    float xv[4][4];
#pragma unroll
    for (int i = 0; i < 4; i++) {
        const float4 v = *(const float4*)(x + (size_t)(mBase + mg + i) * F_);
        xv[i][0] = v.x; xv[i][1] = v.y; xv[i][2] = v.z; xv[i][3] = v.w;
    }

    const int nb = wid * 32 + (lane >> 3);
    const int chunk = (lane & 7) ^ ((lane >> 3) & 7);
    const uint16_t* bsrc0 = W21t + (size_t)h * D_ * D_ + (size_t)(nBase + nb) * D_ + chunk * 8;
    const uint16_t* bsrc1 = W22t + (size_t)h * D_ * D_ + (size_t)(nBase + nb) * D_ + chunk * 8;

    const float* W1h = W1 + (size_t)h * F_ * D_;
    const float* b1h = b1 + (size_t)h * D_;

    floatx4 acc0[4][4], acc1[4][4];
    const floatx4 z4 = {0.f, 0.f, 0.f, 0.f};
#pragma unroll
    for (int mi = 0; mi < 4; mi++)
#pragma unroll
        for (int ni = 0; ni < 4; ni++) { acc0[mi][ni] = z4; acc1[mi][ni] = z4; }

    for (int kt = 0; kt < D_; kt += 64) {
        float2v w1v[4][4], b1v[4];
        {
            const float4 bb0 = *(const float4*)(b1h + kt + k0);
            const float4 bb1 = *(const float4*)(b1h + kt + k0 + 4);
            b1v[0] = (float2v){bb0.x, bb0.y}; b1v[1] = (float2v){bb0.z, bb0.w};
            b1v[2] = (float2v){bb1.x, bb1.y}; b1v[3] = (float2v){bb1.z, bb1.w};
#pragma unroll
            for (int f = 0; f < 4; f++) {
                const float4 a0 = *(const float4*)(W1h + f * D_ + kt + k0);
                const float4 a1 = *(const float4*)(W1h + f * D_ + kt + k0 + 4);
                w1v[f][0] = (float2v){a0.x, a0.y}; w1v[f][1] = (float2v){a0.z, a0.w};
                w1v[f][2] = (float2v){a1.x, a1.y}; w1v[f][3] = (float2v){a1.z, a1.w};
            }
        }
#pragma unroll
        for (int i = 0; i < 4; i++) {
            async16(bsrc0 + kt + i * (8 * D_), (char*)Bt0 + wid * 4096 + i * 1024);
            async16(bsrc1 + kt + i * (8 * D_), (char*)Bt1 + wid * 4096 + i * 1024);
        }
        // h1 compute -> A tile (bf16, swizzled): v_pk_fma_f32 + cheap pack
#pragma unroll
        for (int i = 0; i < 4; i++) {
            const int m = mg + i;
            float2v hv[4];
#pragma unroll
            for (int j = 0; j < 4; j++) hv[j] = b1v[j];
#pragma unroll
            for (int f = 0; f < 4; f++) {
                const float2v xs = {xv[i][f], xv[i][f]};
#pragma unroll
                for (int j = 0; j < 4; j++)
                    hv[j] = __builtin_elementwise_fma(xs, w1v[f][j], hv[j]);
            }
            At[m * 8 + ((t & 7) ^ (m & 7))] =
                make_uint4(packbf(hv[0].x, hv[0].y), packbf(hv[1].x, hv[1].y),
                           packbf(hv[2].x, hv[2].y), packbf(hv[3].x, hv[3].y));
        }
        __syncthreads();
#pragma unroll
        for (int s = 0; s < 2; s++) {
            short8 af[4];
#pragma unroll
            for (int mi = 0; mi < 4; mi++) {
                const int m = wm * 64 + mi * 16 + c15;
                af[mi] = __builtin_bit_cast(short8, At[m * 8 + ((s * 4 + q) ^ (c15 & 7))]);
            }
#pragma unroll
            for (int ni = 0; ni < 4; ni++) {
                const int n = wn * 64 + ni * 16 + c15;
                const int bidx = n * 8 + ((s * 4 + q) ^ (c15 & 7));
                const short8 bf0 = __builtin_bit_cast(short8, Bt0[bidx]);
#pragma unroll
                for (int mi = 0; mi < 4; mi++)
                    acc0[mi][ni] = __builtin_amdgcn_mfma_f32_16x16x32_bf16(af[mi], bf0, acc0[mi][ni], 0, 0, 0);
                const short8 bf1 = __builtin_bit_cast(short8, Bt1[bidx]);
#pragma unroll
                for (int mi = 0; mi < 4; mi++)
                    acc1[mi][ni] = __builtin_amdgcn_mfma_f32_16x16x32_bf16(af[mi], bf1, acc1[mi][ni], 0, 0, 0);
            }
        }
        __syncthreads();
    }

    // ---- Epilogue: bias + relu + (.)@W3 reduction, shuffle-reduce, atomics
#pragma unroll
    for (int p = 0; p < 2; p++) {
        const float* b2p = (p == 0 ? b21 : b22) + (size_t)h * D_;
        const float* W3p = (p == 0 ? W31 : W32) + (size_t)h * D_ * C_;
        float* ab = (p == 0 ? acc31 : acc32) + (size_t)h * B_ * C_;
        float w3x[4], w3y[4], bs[4];
#pragma unroll
        for (int ni = 0; ni < 4; ni++) {
            const int n = nBase + wn * 64 + ni * 16 + c15;
            bs[ni] = b2p[n];
            const float2 w2 = *(const float2*)(W3p + n * 2);
            w3x[ni] = w2.x; w3y[ni] = w2.y;
        }
        float s0[16], s1[16];
#pragma unroll
        for (int mi = 0; mi < 4; mi++)
#pragma unroll
            for (int r = 0; r < 4; r++) {
                float t0 = 0.f, t1 = 0.f;
#pragma unroll
                for (int ni = 0; ni < 4; ni++) {
                    float v = (p == 0 ? acc0[mi][ni][r] : acc1[mi][ni][r]) + bs[ni];
                    v = fmaxf(v, 0.f);
                    t0 = fmaf(v, w3x[ni], t0);
                    t1 = fmaf(v, w3y[ni], t1);
                }
                s0[mi * 4 + r] = t0; s1[mi * 4 + r] = t1;
            }
#pragma unroll
        for (int off = 1; off < 16; off <<= 1)
#pragma unroll
            for (int i = 0; i < 16; i++) {
                s0[i] += __shfl_xor(s0[i], off, 64);
                s1[i] += __shfl_xor(s1[i], off, 64);
            }
        if (c15 == 0) {
#pragma unroll
            for (int mi = 0; mi < 4; mi++)
#pragma unroll
                for (int r = 0; r < 4; r++) {
                    const int row = mBase + wm * 64 + mi * 16 + q * 4 + r;
                    atomicAdd(&ab[row * C_ + 0], s0[mi * 4 + r]);
                    atomicAdd(&ab[row * C_ + 1], s1[mi * 4 + r]);
                }
        }
    }
}

// ---------------------------------------------------------------------------
// Finalize: biases, sigmoid head, CBF-QP correction, softmax-weighted mix
// ---------------------------------------------------------------------------
__global__ __launch_bounds__(256) void k_final(
    const float* __restrict__ x,
    const float* __restrict__ acc31, const float* __restrict__ acc32,
    const float* __restrict__ b31, const float* __restrict__ b32,
    const float* __restrict__ wt, const float* __restrict__ mean,
    const float* __restrict__ stdv, float* __restrict__ out)
{
    const int b = blockIdx.x * 256 + threadIdx.x;
    const float4 xb = *(const float4*)(x + (size_t)b * 4);
    const float px = xb.x * stdv[0] + mean[0];
    const float py = xb.y * stdv[1] + mean[1];
    const float th = xb.z * stdv[2] + mean[2];
    const float v  = xb.w * stdv[3] + mean[3];
    const float dx = px - 40.0f, dy = py - 15.0f;
    const float st = sinf(th), ct = cosf(th);
    const float barrier = dx * dx + dy * dy - 36.0f;
    const float bdot = 2.f * dx * v * ct + 2.f * dy * v * st;
    const float Lf2b = 2.f * v * v;
    const float G0 = -(-2.f * dx * v * st + 2.f * dy * v * ct);
    const float G1 = -(2.f * dx * ct + 2.f * dy * st);
    const float GG = G0 * G0 + G1 * G1;

    float we[H_];
    float wmax = wt[0];
    for (int h = 1; h < H_; h++) wmax = fmaxf(wmax, wt[h]);
    float wsum = 0.f;
    for (int h = 0; h < H_; h++) { we[h] = expf(wt[h] - wmax); wsum += we[h]; }

    float o0 = 0.f, o1 = 0.f;
#pragma unroll
    for (int h = 0; h < H_; h++) {
        const size_t idx = ((size_t)h * B_ + b) * 2;
        const float x310 = acc31[idx]     + b31[h * 2];
        const float x311 = acc31[idx + 1] + b31[h * 2 + 1];
        const float z0 = acc32[idx]     + b32[h * 2];
        const float z1 = acc32[idx + 1] + b32[h * 2 + 1];
        const float x320 = 4.f / (1.f + expf(-z0));
        const float x321 = 4.f / (1.f + expf(-z1));
        const float hr = Lf2b + (x320 + x321) * bdot + x320 * x321 * barrier;
        const float Gu = G0 * x310 + G1 * x311;
        const float lam = fmaxf(Gu - hr, 0.f) / GG;
        o0 += we[h] * (x310 - lam * G0);
        o1 += we[h] * (x311 - lam * G1);
    }
    out[b * 2]     = o0 / wsum;
    out[b * 2 + 1] = o1 / wsum;
}

extern "C" void kernel_launch(void* const* d_in, const int* in_sizes, int n_in,
                              void* d_out, int out_size, void* d_ws, size_t ws_size,
                              hipStream_t stream)
{
    const float* x    = (const float*)d_in[0];
    const float* W1   = (const float*)d_in[1];
    const float* b1   = (const float*)d_in[2];
    const float* W21  = (const float*)d_in[3];
    const float* b21  = (const float*)d_in[4];
    const float* W22  = (const float*)d_in[5];
    const float* b22  = (const float*)d_in[6];
    const float* W31  = (const float*)d_in[7];
    const float* b31  = (const float*)d_in[8];
    const float* W32  = (const float*)d_in[9];
    const float* b32  = (const float*)d_in[10];
    const float* wt   = (const float*)d_in[11];
    const float* mean = (const float*)d_in[12];
    const float* stdv = (const float*)d_in[13];
    float* out = (float*)d_out;

    char* ws = (char*)d_ws;
    uint16_t* W21t = (uint16_t*)(ws);
    uint16_t* W22t = (uint16_t*)(ws + 83886080);
    float* acc31   = (float*)(ws + 167772160);
    float* acc32   = (float*)(ws + 169082880);

    k_convert<<<dim3(32, 32, 20), 256, 0, stream>>>(W21, W22, W21t, W22t);
    k_zero<<<dim3(640), 256, 0, stream>>>((uint4*)acc31, 163840);
    k_gemm<<<dim3(128, 16, 10), 256, 0, stream>>>(x, W1, b1, W21t, W22t,
                                                  b21, b22, W31, W32, acc31, acc32);
    k_final<<<dim3(64), 256, 0, stream>>>(x, acc31, acc32, b31, b32, wt, mean, stdv, out);
}